// Round 3
// baseline (221.912 us; speedup 1.0000x reference)
//
#include <hip/hip_runtime.h>

#define DEVINL __device__ __forceinline__

typedef _Float16 h2  __attribute__((ext_vector_type(2)));
typedef _Float16 h4v __attribute__((ext_vector_type(4)));
typedef _Float16 h8v __attribute__((ext_vector_type(8)));

DEVINL float fexp2(float x){ return __builtin_amdgcn_exp2f(x); }
DEVINL float frcp (float x){ return __builtin_amdgcn_rcpf(x); }

#if __has_builtin(__builtin_amdgcn_fdot2)
DEVINL float dot2(h2 a, h2 b, float c){ return __builtin_amdgcn_fdot2(a, b, c, false); }
#else
DEVINL float dot2(h2 a, h2 b, float c){
  return fmaf((float)a.x, (float)b.x, fmaf((float)a.y, (float)b.y, c));
}
#endif

// ---------------------------------------------------------------------------
// Kernel 1: precompute per-(dir, idx, lane) input-gate table
//   G = { Wr_e·e + bih_r + bhh_r,  Wz_e·e + bih_z + bhh_z,  Wn_e·e + bih_n, 0 }
// plus the static part of out[b].
// ---------------------------------------------------------------------------
template<int H>
DEVINL void pre_entry(int t, const float* __restrict__ emb,
                      const float* __restrict__ Wih_f, const float* __restrict__ bih_f, const float* __restrict__ bhh_f,
                      const float* __restrict__ Wih_b, const float* __restrict__ bih_b, const float* __restrict__ bhh_b,
                      float4* __restrict__ G, int N)
{
  constexpr int E = H - 1;
  const int dir = t / (N * H);
  const int r   = t - dir * (N * H);
  const int idx = r / H;
  const int li  = r - idx * H;
  const float* Wih = dir ? Wih_b : Wih_f;
  const float* bih = dir ? bih_b : bih_f;
  const float* bhh = dir ? bhh_b : bhh_f;
  const float* e = emb + (size_t)idx * E;
  float gr = bih[li]       + bhh[li];
  float gz = bih[H + li]   + bhh[H + li];
  float gn = bih[2*H + li];
#pragma unroll
  for (int q = 0; q < E; q++){
    const float ev = e[q];
    gr = fmaf(Wih[(size_t)( li     )*H + q], ev, gr);
    gz = fmaf(Wih[(size_t)( H + li )*H + q], ev, gz);
    gn = fmaf(Wih[(size_t)(2*H + li)*H + q], ev, gn);
  }
  G[(size_t)(dir * N + idx) * H + li] = make_float4(gr, gz, gn, 0.f);
}

__global__ __launch_bounds__(256) void pre_kernel(
    const float* __restrict__ emb_dp, const float* __restrict__ emb_cp,
    const float* __restrict__ Wih_dpf, const float* __restrict__ bih_dpf, const float* __restrict__ bhh_dpf,
    const float* __restrict__ Wih_dpb, const float* __restrict__ bih_dpb, const float* __restrict__ bhh_dpb,
    const float* __restrict__ Wih_cpf, const float* __restrict__ bih_cpf, const float* __restrict__ bhh_cpf,
    const float* __restrict__ Wih_cpb, const float* __restrict__ bih_cpb, const float* __restrict__ bhh_cpb,
    const float* __restrict__ stat, const float* __restrict__ fc_all_w, const float* __restrict__ fc_all_b,
    const float* __restrict__ fc_dp_b, const float* __restrict__ fc_cp_b,
    float4* __restrict__ Gdp, float4* __restrict__ Gcp, float* __restrict__ out)
{
  constexpr int NDP_E = 2 * 4096 * 9;    // 73728
  constexpr int NCP_E = 2 * 10000 * 11;  // 220000
  const int t = blockIdx.x * 256 + threadIdx.x;
  if (t < NDP_E){
    pre_entry<9>(t, emb_dp, Wih_dpf, bih_dpf, bhh_dpf, Wih_dpb, bih_dpb, bhh_dpb, Gdp, 4096);
  } else if (t < NDP_E + NCP_E){
    pre_entry<11>(t - NDP_E, emb_cp, Wih_cpf, bih_cpf, bhh_cpf, Wih_cpb, bih_cpb, bhh_cpb, Gcp, 10000);
  } else if (t < NDP_E + NCP_E + 4096){
    const int b = t - (NDP_E + NCP_E);
    float s = fc_all_b[0] + fc_all_w[20]*fc_dp_b[0] + fc_all_w[21]*fc_cp_b[0];
    const float* st = stat + (size_t)b * 20;
#pragma unroll
    for (int k = 0; k < 20; k++) s = fmaf(fc_all_w[k], st[k], s);
    out[b] = s;
  }
}

// ---------------------------------------------------------------------------
// Kernel 2: fused GRU. Group of H lanes per (batch, direction) sequence.
// DIR compile-time (no reversal selects); recurrent matvec via v_dot2_f32_f16
// with fp16 h broadcast through a per-group LDS slot (within-wave, no barriers).
// ---------------------------------------------------------------------------
template<int H, int GPW, int N, int DIR>
DEVINL void gru_run(int gid, int li, int slot,
    const int* __restrict__ seq, const float* __restrict__ tim,
    const float4* __restrict__ Gtab,
    const float* __restrict__ Wih, const float* __restrict__ Whh, const float* __restrict__ bhh,
    const float* __restrict__ fc_w, float wt,
    float* __restrict__ out, _Float16* hbuf)
{
  constexpr int S  = 512;
  constexpr int NP = (H + 1) / 2;
  const int b = gid & 4095;

  // dt-column weights (f32) and n-gate recurrent bias
  const float Wrd = Wih[( li      )*H + (H-1)];
  const float Wzd = Wih[( H + li  )*H + (H-1)];
  const float Wnd = Wih[(2*H + li )*H + (H-1)];
  const float bhn = bhh[2*H + li];

  // recurrent rows as f16 pairs (pad weight = 0)
  h2 Urp[NP], Uzp[NP], Unp[NP];
#pragma unroll
  for (int j = 0; j < NP; j++){
    const int q0 = 2*j, q1 = 2*j + 1;
    h2 v;
    v.x = (_Float16)Whh[( li      )*H + q0];
    v.y = (_Float16)((q1 < H) ? Whh[( li      )*H + q1] : 0.f);
    Urp[j] = v;
    v.x = (_Float16)Whh[( H + li  )*H + q0];
    v.y = (_Float16)((q1 < H) ? Whh[( H + li  )*H + q1] : 0.f);
    Uzp[j] = v;
    v.x = (_Float16)Whh[(2*H + li )*H + q0];
    v.y = (_Float16)((q1 < H) ? Whh[(2*H + li )*H + q1] : 0.f);
    Unp[j] = v;
  }

  const int gb = slot * 24;                       // half-element offset of group slot (48B stride)
  if (li == 0) hbuf[gb + H] = (_Float16)0.f;      // zero the pad half read each step

  const int*   sp = seq + (size_t)b * S;
  const float* tp = tim + (size_t)b * S;
  const char*  gbase = (const char*)(Gtab + ((size_t)DIR * N) * H + li);

  h2 hp[NP];
#pragma unroll
  for (int j = 0; j < NP; j++){ h2 z0; z0.x = (_Float16)0.f; z0.y = (_Float16)0.f; hp[j] = z0; }
  float hmine = 0.f, prev = 0.f;

  int ic[4]; float tc[4];
  int icn[4] = {0,0,0,0}; float tcn[4] = {0,0,0,0};
  {
    const int p0 = DIR ? (S - 4) : 0;
    int4   iv = *reinterpret_cast<const int4*  >(sp + p0);
    float4 tv = *reinterpret_cast<const float4*>(tp + p0);
    if constexpr (DIR){ ic[0]=iv.w; ic[1]=iv.z; ic[2]=iv.y; ic[3]=iv.x;
                        tc[0]=tv.w; tc[1]=tv.z; tc[2]=tv.y; tc[3]=tv.x; }
    else              { ic[0]=iv.x; ic[1]=iv.y; ic[2]=iv.z; ic[3]=iv.w;
                        tc[0]=tv.x; tc[1]=tv.y; tc[2]=tv.z; tc[3]=tv.w; }
  }

  // depth-3 gather ring
  float4 Gb[4];
  Gb[0] = *(const float4*)(gbase + (unsigned)ic[0] * (unsigned)(H*16));
  Gb[1] = *(const float4*)(gbase + (unsigned)ic[1] * (unsigned)(H*16));
  Gb[2] = *(const float4*)(gbase + (unsigned)ic[2] * (unsigned)(H*16));

#pragma unroll 1
  for (int c = 0; c < S/4; ++c){
    if (c < S/4 - 1){
      const int p0 = DIR ? (S - 8 - 4*c) : (4*c + 4);
      int4   iv = *reinterpret_cast<const int4*  >(sp + p0);
      float4 tv = *reinterpret_cast<const float4*>(tp + p0);
      if constexpr (DIR){ icn[0]=iv.w; icn[1]=iv.z; icn[2]=iv.y; icn[3]=iv.x;
                          tcn[0]=tv.w; tcn[1]=tv.z; tcn[2]=tv.y; tcn[3]=tv.x; }
      else              { icn[0]=iv.x; icn[1]=iv.y; icn[2]=iv.z; icn[3]=iv.w;
                          tcn[0]=tv.x; tcn[1]=tv.y; tcn[2]=tv.z; tcn[3]=tv.w; }
    }
#pragma unroll
    for (int k = 0; k < 4; k++){
      const float4 g4 = Gb[k];
      // prefetch step c*4+k+3 (stale icn on last chunk: valid indices, unused)
      {
        const int pidx = (k == 0) ? ic[3] : icn[k-1];
        Gb[(k+3)&3] = *(const float4*)(gbase + (unsigned)pidx * (unsigned)(H*16));
      }

      const float tcur = tc[k];
      const float dtv = fmaxf(tcur - prev, 0.f); prev = tcur;

      float ar = fmaf(Wrd, dtv, g4.x);
      float az = fmaf(Wzd, dtv, g4.y);
      float an = fmaf(Wnd, dtv, g4.z);
      float hn = bhn;
#pragma unroll
      for (int j = 0; j < NP; j++){
        ar = dot2(Urp[j], hp[j], ar);
        az = dot2(Uzp[j], hp[j], az);
        hn = dot2(Unp[j], hp[j], hn);
      }
      const float r  = frcp(1.f + fexp2(-1.4426950408889634f * ar));
      const float z  = frcp(1.f + fexp2(-1.4426950408889634f * az));
      const float ec = fexp2(2.885390081777927f * fmaf(r, hn, an));
      const float n  = fmaf(-2.f, frcp(1.f + ec), 1.f);
      hmine = fmaf(z, hmine - n, n);            // (1-z)*n + z*h

      hbuf[gb + li] = (_Float16)hmine;          // publish own element (2B)
      __builtin_amdgcn_wave_barrier();
      asm volatile("" ::: "memory");            // in-order DS pipe orders write->reads

      h8v hv = *reinterpret_cast<const h8v*>(hbuf + gb);
      hp[0] = __builtin_shufflevector(hv, hv, 0, 1);
      hp[1] = __builtin_shufflevector(hv, hv, 2, 3);
      hp[2] = __builtin_shufflevector(hv, hv, 4, 5);
      hp[3] = __builtin_shufflevector(hv, hv, 6, 7);
      if constexpr (H == 9){
        hp[4] = *reinterpret_cast<const h2*>(hbuf + gb + 8);
      } else {
        h4v t4 = *reinterpret_cast<const h4v*>(hbuf + gb + 8);
        hp[4] = __builtin_shufflevector(t4, t4, 0, 1);
        hp[5] = __builtin_shufflevector(t4, t4, 2, 3);
      }
    }
#pragma unroll
    for (int k2 = 0; k2 < 4; k2++){ ic[k2] = icn[k2]; tc[k2] = tcn[k2]; }
  }

  // own-element contribution (full f32 precision), one atomic per lane
  atomicAdd(out + b, wt * fc_w[DIR*H + li] * hmine);
}

__global__ __launch_bounds__(256) void gru_fused(
    const int* __restrict__ dp,  const float* __restrict__ dp_t,
    const int* __restrict__ cp,  const float* __restrict__ cp_t,
    const float4* __restrict__ Gdp, const float4* __restrict__ Gcp,
    const float* __restrict__ Wih_dpf, const float* __restrict__ Whh_dpf, const float* __restrict__ bhh_dpf,
    const float* __restrict__ Wih_dpb, const float* __restrict__ Whh_dpb, const float* __restrict__ bhh_dpb,
    const float* __restrict__ Wih_cpf, const float* __restrict__ Whh_cpf, const float* __restrict__ bhh_cpf,
    const float* __restrict__ Wih_cpb, const float* __restrict__ Whh_cpb, const float* __restrict__ bhh_cpb,
    const float* __restrict__ fc_dp_w, const float* __restrict__ fc_cp_w, const float* __restrict__ fc_all_w,
    float* __restrict__ out, int DP_BLOCKS)
{
  __shared__ __align__(16) _Float16 hbuf[28*24 + 8];
  const int tid = threadIdx.x, wave = tid >> 6, lane = tid & 63;

  if ((int)blockIdx.x < DP_BLOCKS){
    constexpr int H = 9, GPW = 7;
    const int g = lane / H;
    if (g >= GPW) return;
    const int li  = lane - g * H;
    const int gid = blockIdx.x * (4*GPW) + wave * GPW + g;
    if (gid >= 8192) return;
    const int slot = wave * GPW + g;
    const float wt = fc_all_w[20];
    if ((gid >> 12) == 0)
      gru_run<9,7,4096,0>(gid, li, slot, dp, dp_t, Gdp, Wih_dpf, Whh_dpf, bhh_dpf, fc_dp_w, wt, out, hbuf);
    else
      gru_run<9,7,4096,1>(gid, li, slot, dp, dp_t, Gdp, Wih_dpb, Whh_dpb, bhh_dpb, fc_dp_w, wt, out, hbuf);
  } else {
    constexpr int H = 11, GPW = 5;
    const int blk = blockIdx.x - DP_BLOCKS;
    const int g = lane / H;
    if (g >= GPW) return;
    const int li  = lane - g * H;
    const int gid = blk * (4*GPW) + wave * GPW + g;
    if (gid >= 8192) return;
    const int slot = wave * GPW + g;
    const float wt = fc_all_w[21];
    if ((gid >> 12) == 0)
      gru_run<11,5,10000,0>(gid, li, slot, cp, cp_t, Gcp, Wih_cpf, Whh_cpf, bhh_cpf, fc_cp_w, wt, out, hbuf);
    else
      gru_run<11,5,10000,1>(gid, li, slot, cp, cp_t, Gcp, Wih_cpb, Whh_cpb, bhh_cpb, fc_cp_w, wt, out, hbuf);
  }
}

extern "C" void kernel_launch(void* const* d_in, const int* in_sizes, int n_in,
                              void* d_out, int out_size, void* d_ws, size_t ws_size,
                              hipStream_t stream)
{
  const float* stat   = (const float*)d_in[0];
  const int*   dp     = (const int*)  d_in[1];
  const int*   cp     = (const int*)  d_in[2];
  const float* dp_t   = (const float*)d_in[3];
  const float* cp_t   = (const float*)d_in[4];
  const float* emb_dp = (const float*)d_in[5];
  const float* emb_cp = (const float*)d_in[6];

  const float* Wih_dpf = (const float*)d_in[7];
  const float* Whh_dpf = (const float*)d_in[8];
  const float* bih_dpf = (const float*)d_in[9];
  const float* bhh_dpf = (const float*)d_in[10];
  const float* Wih_dpb = (const float*)d_in[11];
  const float* Whh_dpb = (const float*)d_in[12];
  const float* bih_dpb = (const float*)d_in[13];
  const float* bhh_dpb = (const float*)d_in[14];
  const float* Wih_cpf = (const float*)d_in[15];
  const float* Whh_cpf = (const float*)d_in[16];
  const float* bih_cpf = (const float*)d_in[17];
  const float* bhh_cpf = (const float*)d_in[18];
  const float* Wih_cpb = (const float*)d_in[19];
  const float* Whh_cpb = (const float*)d_in[20];
  const float* bih_cpb = (const float*)d_in[21];
  const float* bhh_cpb = (const float*)d_in[22];

  const float* fc_dp_w  = (const float*)d_in[23];
  const float* fc_dp_b  = (const float*)d_in[24];
  const float* fc_cp_w  = (const float*)d_in[25];
  const float* fc_cp_b  = (const float*)d_in[26];
  const float* fc_all_w = (const float*)d_in[27];
  const float* fc_all_b = (const float*)d_in[28];

  float* out = (float*)d_out;

  // workspace: dp table (2*4096*9 float4 = 1.18 MB), cp table (2*10000*11 float4 = 3.52 MB)
  float4* Gdp = (float4*)d_ws;
  float4* Gcp = (float4*)((char*)d_ws + (size_t)(2*4096*9) * sizeof(float4));

  {
    const int total = 2*4096*9 + 2*10000*11 + 4096;
    const int blocks = (total + 255) / 256;
    pre_kernel<<<blocks, 256, 0, stream>>>(
        emb_dp, emb_cp,
        Wih_dpf, bih_dpf, bhh_dpf, Wih_dpb, bih_dpb, bhh_dpb,
        Wih_cpf, bih_cpf, bhh_cpf, Wih_cpb, bih_cpb, bhh_cpb,
        stat, fc_all_w, fc_all_b, fc_dp_b, fc_cp_b,
        Gdp, Gcp, out);
  }

  {
    const int DP_BLOCKS = (8192 + 27) / 28;   // H=9,  7 groups/wave
    const int CP_BLOCKS = (8192 + 19) / 20;   // H=11, 5 groups/wave
    gru_fused<<<DP_BLOCKS + CP_BLOCKS, 256, 0, stream>>>(
        dp, dp_t, cp, cp_t, Gdp, Gcp,
        Wih_dpf, Whh_dpf, bhh_dpf, Wih_dpb, Whh_dpb, bhh_dpb,
        Wih_cpf, Whh_cpf, bhh_cpf, Wih_cpb, Whh_cpb, bhh_cpb,
        fc_dp_w, fc_cp_w, fc_all_w, out, DP_BLOCKS);
  }
}